// Round 11
// baseline (90.948 us; speedup 1.0000x reference)
//
#include <hip/hip_runtime.h>
#include <hip/hip_bf16.h>

typedef float          f32x4  __attribute__((ext_vector_type(4)));
typedef __bf16         bf16x8 __attribute__((ext_vector_type(8)));
typedef unsigned short u16x8  __attribute__((ext_vector_type(8)));
typedef unsigned int   u32;

#define DEV static __device__ __forceinline__

static constexpr int   NT       = 65536;            // (262144*4)/16 16-row tiles
static constexpr float SCALE_Q2 = 0.2550349f;       // (1/sqrt(32)) * log2(e)  -> scores in log2 units

DEV unsigned short f2bf(float f) {
  return __builtin_bit_cast(unsigned short, __float2bfloat16(f));
}
// single-instruction RNE pair convert (gfx950)
DEV u32 pk2(float lo, float hi) {
  u32 r;
  asm("v_cvt_pk_bf16_f32 %0, %1, %2" : "=v"(r) : "v"(lo), "v"(hi));
  return r;
}

DEV u16x8 pack8(f32x4 a, f32x4 b) {
  uint4 q;
  q.x = pk2(a[0], a[1]); q.y = pk2(a[2], a[3]);
  q.z = pk2(b[0], b[1]); q.w = pk2(b[2], b[3]);
  return __builtin_bit_cast(u16x8, q);
}

DEV f32x4 mfma(u16x8 a, u16x8 b, f32x4 c) {
  return __builtin_amdgcn_mfma_f32_16x16x32_bf16(
      __builtin_bit_cast(bf16x8, a), __builtin_bit_cast(bf16x8, b), c, 0, 0, 0);
}
DEV void wait_lds() {
  asm volatile("s_waitcnt lgkmcnt(0)" ::: "memory");
  __builtin_amdgcn_sched_barrier(0);
}

// read a weight fragment from the block-shared LDS table; the OFFSET is laundered
// through a volatile asm so the load stays in-loop (no LICM re-hoist -> no register
// pressure re-inflation) while the base remains a recognizable LDS object (ds_read).
DEV u16x8 ldfrag(const u32* base, int idx, int l) {
  int off = (idx * 64 + l) * 4;
  asm volatile("" : "+v"(off));
  return __builtin_bit_cast(u16x8, *(const uint4*)(base + off));
}

// A-fragment of W^T for dout-column `col`, k-rows k0..k0+7.  W row-major [K][N], f32.
DEV u16x8 build_frag(const float* W, int N, int k0, int col, float scale) {
  u16x8 f;
#pragma unroll
  for (int e = 0; e < 8; ++e)
    f[e] = f2bf(W[(k0 + e) * N + col] * scale);
  return f;
}
DEV u16x8 fold_frag(u16x8 f, const float* gv) {
  u16x8 o;
#pragma unroll
  for (int e = 0; e < 8; ++e) {
    union { u32 i; float v; } u; u.i = ((u32)f[e]) << 16;
    o[e] = f2bf(u.v * gv[e]);
  }
  return o;
}

DEV void conv_wr(u32* buf, int wb, f32x4 a0, f32x4 a1) {
  buf[wb + 0] = pk2(a0[0], a0[1]);
  buf[wb + 1] = pk2(a0[2], a0[3]);
  buf[wb + 8] = pk2(a1[0], a1[1]);
  buf[wb + 9] = pk2(a1[2], a1[3]);
}
DEV u16x8 conv_rd(const u32* buf, int rb) {
  return __builtin_bit_cast(u16x8, *(const uint4*)(buf + rb));
}

DEV void ln_stats(f32x4 a, f32x4 b, float& rs, float& nm) {
  float s1 = 0.f, s2 = 0.f;
#pragma unroll
  for (int i = 0; i < 4; ++i) { s1 += a[i]; s2 = fmaf(a[i], a[i], s2); }
#pragma unroll
  for (int i = 0; i < 4; ++i) { s1 += b[i]; s2 = fmaf(b[i], b[i], s2); }
  s1 += __shfl_xor(s1, 16); s2 += __shfl_xor(s2, 16);
  s1 += __shfl_xor(s1, 32); s2 += __shfl_xor(s2, 32);
  const float m   = s1 * 0.03125f;
  const float var = fmaf(s2, 0.03125f, -m * m);
  rs = __builtin_amdgcn_rsqf(var + 1e-5f);
  nm = -m * rs;
}

// gelu(u) = u - u/(e+1),  e = exp2(u*(2.3022083 + 0.1029428 u^2))   (LOG2E pre-folded)
DEV float gelu_t(float u) {
  const float z = u * fmaf(u * u, 0.1029428f, 2.3022083f);
  const float e = __builtin_amdgcn_exp2f(z);
  return fmaf(-u, __builtin_amdgcn_rcpf(e + 1.0f), u);
}

__global__ __launch_bounds__(256) void vit_fused(
    const float* __restrict__ x,
    const float* __restrict__ wpe, const float* __restrict__ bpe,
    const float* __restrict__ pos,
    const float* __restrict__ ln1g, const float* __restrict__ ln1b,
    const float* __restrict__ wq, const float* __restrict__ bq,
    const float* __restrict__ wk, const float* __restrict__ bk,
    const float* __restrict__ wv, const float* __restrict__ bv,
    const float* __restrict__ wo, const float* __restrict__ bo,
    const float* __restrict__ ln2g, const float* __restrict__ ln2b,
    const float* __restrict__ w1, const float* __restrict__ bf1,
    const float* __restrict__ w2, const float* __restrict__ bf2,
    float* __restrict__ out) {
  const int tid = (int)threadIdx.x;
  const int wid = tid >> 6;
  const int l   = tid & 63;
  const int r15 = l & 15;        // row within 16-row tile (= 4 batches x 4 tokens)
  const int lg  = l >> 4;        // lane group 0..3
  const int tk  = l & 3;         // token index of this row

  __shared__ alignas(16) u32   s_conv[4][2][320];  // 10.0 KB per-wave conv buffers
  __shared__ alignas(16) float s_vh[4][576];       //  9.0 KB v-staging / vo-tile / MLP-h
  __shared__ alignas(16) u32   s_wf[18 * 64 * 4];  // 18.0 KB block-shared weight fragments
  u32*   bufA = s_conv[wid][0];
  u32*   bufB = s_conv[wid][1];
  float* vS   = s_vh[wid];
  u32*   vStg = (u32*)s_vh[wid];
  u32*   hB   = (u32*)s_vh[wid];
  const u32* wf = s_wf;

  // ---------------- init: frag table (wave 0) + per-wave folded C-operands ----------------
  float g1v[8], g2v[8];
#pragma unroll
  for (int e = 0; e < 8; ++e) { g1v[e] = ln1g[8 * lg + e]; g2v[e] = ln2g[8 * lg + e]; }
  const u16x8 b1f = pack8(*(const f32x4*)(ln1b + 8 * lg), *(const f32x4*)(ln1b + 8 * lg + 4));
  const u16x8 b2f = pack8(*(const f32x4*)(ln2b + 8 * lg), *(const f32x4*)(ln2b + 8 * lg + 4));

  f32x4 comboC[2], bqC[2], bkC[2], bvC[2], boC[2], bf2C[2], bf1C[4];

#pragma unroll
  for (int H = 0; H < 2; ++H) {
    const int dc  = 16 * H + 4 * lg;
    const int col = 16 * H + r15;
    f32x4 cq, ck, cv, cmb, cbo, cb2;
#pragma unroll
    for (int i = 0; i < 4; ++i) {
      const int d = dc + i;
      cmb[i] = bpe[d] + pos[tk * 32 + d];
      cq[i]  = SCALE_Q2 * bq[d];
      ck[i]  = bk[d];
      cv[i]  = bv[d];
      cbo[i] = bo[d];
      cb2[i] = bf2[d];
    }
    comboC[H] = cmb; boC[H] = cbo; bf2C[H] = cb2;
    const u16x8 rq = build_frag(wq, 32, 8 * lg, col, SCALE_Q2);
    const u16x8 rk = build_frag(wk, 32, 8 * lg, col, 1.f);
    const u16x8 rv = build_frag(wv, 32, 8 * lg, col, 1.f);
    bqC[H] = mfma(rq, b1f, cq);        // SCALE'*(bq + ln1_b @ wq)
    bkC[H] = mfma(rk, b1f, ck);
    bvC[H] = mfma(rv, b1f, cv);
    if (wid == 0) {
      *(uint4*)&s_wf[((0 + H) * 64 + l) * 4]  = __builtin_bit_cast(uint4, build_frag(wpe, 32, 8 * lg, col, 1.f));
      *(uint4*)&s_wf[((2 + H) * 64 + l) * 4]  = __builtin_bit_cast(uint4, fold_frag(rq, g1v));
      *(uint4*)&s_wf[((4 + H) * 64 + l) * 4]  = __builtin_bit_cast(uint4, fold_frag(rk, g1v));
      *(uint4*)&s_wf[((6 + H) * 64 + l) * 4]  = __builtin_bit_cast(uint4, fold_frag(rv, g1v));
      *(uint4*)&s_wf[((8 + H) * 64 + l) * 4]  = __builtin_bit_cast(uint4, build_frag(wo, 32, 8 * lg, col, 1.f));
      *(uint4*)&s_wf[((14 + H) * 64 + l) * 4] = __builtin_bit_cast(uint4, build_frag(w2, 32, 8 * lg,      col, 1.f));
      *(uint4*)&s_wf[((16 + H) * 64 + l) * 4] = __builtin_bit_cast(uint4, build_frag(w2, 32, 32 + 8 * lg, col, 1.f));
    }
  }
#pragma unroll
  for (int Hp = 0; Hp < 4; ++Hp) {
    const int col = 16 * Hp + r15;
    const u16x8 r1 = build_frag(w1, 64, 8 * lg, col, 1.f);
    f32x4 c1;
#pragma unroll
    for (int i = 0; i < 4; ++i) c1[i] = bf1[16 * Hp + 4 * lg + i];
    bf1C[Hp] = mfma(r1, b2f, c1);      // bf1 + ln2_b @ w1
    if (wid == 0)
      *(uint4*)&s_wf[((10 + Hp) * 64 + l) * 4] = __builtin_bit_cast(uint4, fold_frag(r1, g2v));
  }
  __syncthreads();

  // ---------------- main loop ----------------
  const f32x4 zero4 = {0.f, 0.f, 0.f, 0.f};
  const int stride = (int)(gridDim.x << 2);
  int tile = (int)(blockIdx.x << 2) | wid;

  const float* xp = x + (size_t)(tile * 16 + r15) * 32 + 8 * lg;
  f32x4 xv0 = *(const f32x4*)(xp);
  f32x4 xv1 = *(const f32x4*)(xp + 4);

  // prologue: fetch first wpe fragments
  u16x8 fpe0 = ldfrag(wf, 0, l), fpe1 = ldfrag(wf, 1, l);
  wait_lds();

  for (; tile < NT; tile += stride) {
    const int nxt = tile + stride;
    f32x4 nx0 = xv0, nx1 = xv1;
    if (nxt < NT) {
      const float* np_ = x + (size_t)(nxt * 16 + r15) * 32 + 8 * lg;
      nx0 = *(const f32x4*)(np_);
      nx1 = *(const f32x4*)(np_ + 4);
    }
    const u16x8 xf = pack8(xv0, xv1);

    // S0: patch-embed + pos : residual base x1 ; LN1 ; stage xa
    f32x4 x1a = mfma(fpe0, xf, comboC[0]);
    f32x4 x1b = mfma(fpe1, xf, comboC[1]);
    float rs, nm;
    ln_stats(x1a, x1b, rs, nm);
    f32x4 ya, yb;
#pragma unroll
    for (int i = 0; i < 4; ++i) { ya[i] = fmaf(x1a[i], rs, nm); yb[i] = fmaf(x1b[i], rs, nm); }
    const int wb = r15 * 20 + 2 * lg;
    const int rb = r15 * 20 + 4 * lg;
    conv_wr(bufA, wb, ya, yb);
    const u16x8 fq0 = ldfrag(wf, 2, l), fq1 = ldfrag(wf, 3, l);
    const u16x8 fk0 = ldfrag(wf, 4, l), fk1 = ldfrag(wf, 5, l);
    const u16x8 fv0 = ldfrag(wf, 6, l), fv1 = ldfrag(wf, 7, l);
    wait_lds();

    // S1: qkv projections ; stage q,k,v
    const u16x8 xaf = conv_rd(bufA, rb);
    const f32x4 qa0 = mfma(fq0, xaf, bqC[0]);
    const f32x4 qa1 = mfma(fq1, xaf, bqC[1]);
    const f32x4 ka0 = mfma(fk0, xaf, bkC[0]);
    const f32x4 ka1 = mfma(fk1, xaf, bkC[1]);
    const f32x4 va0 = mfma(fv0, xaf, bvC[0]);
    const f32x4 va1 = mfma(fv1, xaf, bvC[1]);
    conv_wr(bufB, wb, qa0, qa1);
    conv_wr(bufA, wb, ka0, ka1);
    conv_wr(vStg, wb, va0, va1);
    const u16x8 fo0 = ldfrag(wf, 8, l), fo1 = ldfrag(wf, 9, l);
    wait_lds();

    // S2: vo = v@wo + bo (reassociated) ; scores ; softmax ; stage vo ; bpermute attn
    const u16x8 qf = conv_rd(bufB, rb);
    const u16x8 kf = conv_rd(bufA, rb);
    const u16x8 vf = conv_rd(vStg, rb);
    const f32x4 vo0 = mfma(fo0, vf, boC[0]);
    const f32x4 vo1 = mfma(fo1, vf, boC[1]);
    const f32x4 sc = mfma(kf, qf, zero4);
    const float mx = fmaxf(fmaxf(sc[0], sc[1]), fmaxf(sc[2], sc[3]));
    const float e0 = __builtin_amdgcn_exp2f(sc[0] - mx);
    const float e1 = __builtin_amdgcn_exp2f(sc[1] - mx);
    const float e2 = __builtin_amdgcn_exp2f(sc[2] - mx);
    const float e3 = __builtin_amdgcn_exp2f(sc[3] - mx);
    const float rc = __builtin_amdgcn_rcpf((e0 + e1) + (e2 + e3));
    *(f32x4*)(vS + r15 * 36 + 4 * lg)      = vo0;
    *(f32x4*)(vS + r15 * 36 + 16 + 4 * lg) = vo1;
    const int srcb = (16 * (r15 >> 2) + r15) << 2;
    f32x4 atv;
    atv[0] = __builtin_bit_cast(float, __builtin_amdgcn_ds_bpermute(srcb, __builtin_bit_cast(int, e0 * rc)));
    atv[1] = __builtin_bit_cast(float, __builtin_amdgcn_ds_bpermute(srcb, __builtin_bit_cast(int, e1 * rc)));
    atv[2] = __builtin_bit_cast(float, __builtin_amdgcn_ds_bpermute(srcb, __builtin_bit_cast(int, e2 * rc)));
    atv[3] = __builtin_bit_cast(float, __builtin_amdgcn_ds_bpermute(srcb, __builtin_bit_cast(int, e3 * rc)));
    wait_lds();

    // S3: x2 = x1 + attn-mix(vo) ; LN2 ; stage xb
    f32x4 m0 = zero4, m1 = zero4;
#pragma unroll
    for (int j = 0; j < 4; ++j) {
      const f32x4 v0 = *(const f32x4*)(vS + ((r15 & 12) + j) * 36 + 4 * lg);
      const f32x4 v1 = *(const f32x4*)(vS + ((r15 & 12) + j) * 36 + 16 + 4 * lg);
      m0 += atv[j] * v0;
      m1 += atv[j] * v1;
    }
    const f32x4 x2a = x1a + m0;
    const f32x4 x2b = x1b + m1;
    ln_stats(x2a, x2b, rs, nm);
#pragma unroll
    for (int i = 0; i < 4; ++i) { ya[i] = fmaf(x2a[i], rs, nm); yb[i] = fmaf(x2b[i], rs, nm); }
    conv_wr(bufA, wb, ya, yb);
    const u16x8 f10 = ldfrag(wf, 10, l), f11 = ldfrag(wf, 11, l);
    const u16x8 f12 = ldfrag(wf, 12, l), f13 = ldfrag(wf, 13, l);
    wait_lds();

    // S4: MLP up + gelu ; stage h
    const u16x8 xbf = conv_rd(bufA, rb);
    {
      const f32x4 h = mfma(f10, xbf, bf1C[0]);
      const int hb = r15 * 36 + 2 * lg;
      hB[hb]     = pk2(gelu_t(h[0]), gelu_t(h[1]));
      hB[hb + 1] = pk2(gelu_t(h[2]), gelu_t(h[3]));
    }
    {
      const f32x4 h = mfma(f11, xbf, bf1C[1]);
      const int hb = r15 * 36 + 8 + 2 * lg;
      hB[hb]     = pk2(gelu_t(h[0]), gelu_t(h[1]));
      hB[hb + 1] = pk2(gelu_t(h[2]), gelu_t(h[3]));
    }
    {
      const f32x4 h = mfma(f12, xbf, bf1C[2]);
      const int hb = r15 * 36 + 16 + 2 * lg;
      hB[hb]     = pk2(gelu_t(h[0]), gelu_t(h[1]));
      hB[hb + 1] = pk2(gelu_t(h[2]), gelu_t(h[3]));
    }
    {
      const f32x4 h = mfma(f13, xbf, bf1C[3]);
      const int hb = r15 * 36 + 24 + 2 * lg;
      hB[hb]     = pk2(gelu_t(h[0]), gelu_t(h[1]));
      hB[hb + 1] = pk2(gelu_t(h[2]), gelu_t(h[3]));
    }
    const u16x8 f20 = ldfrag(wf, 14, l), f21 = ldfrag(wf, 15, l);
    const u16x8 f22 = ldfrag(wf, 16, l), f23 = ldfrag(wf, 17, l);
    fpe0 = ldfrag(wf, 0, l); fpe1 = ldfrag(wf, 1, l);   // next iteration
    wait_lds();

    // S5: MLP down + residual ; store
    const u16x8 hf0 = __builtin_bit_cast(u16x8, *(const uint4*)(hB + r15 * 36 + 4 * lg));
    const u16x8 hf1 = __builtin_bit_cast(u16x8, *(const uint4*)(hB + r15 * 36 + 16 + 4 * lg));
    f32x4 o0 = x2a + bf2C[0];
    f32x4 o1 = x2b + bf2C[1];
    o0 = mfma(f20, hf0, o0);
    o0 = mfma(f22, hf1, o0);
    o1 = mfma(f21, hf0, o1);
    o1 = mfma(f23, hf1, o1);

    float* op = out + (size_t)(tile * 16 + r15) * 32;
    *(f32x4*)(op + 4 * lg)      = o0;
    *(f32x4*)(op + 16 + 4 * lg) = o1;

    xv0 = nx0; xv1 = nx1;
  }
}

extern "C" void kernel_launch(void* const* d_in, const int* in_sizes, int n_in,
                              void* d_out, int out_size, void* d_ws, size_t ws_size,
                              hipStream_t stream) {
  (void)in_sizes; (void)n_in; (void)d_ws; (void)ws_size; (void)out_size;
  const float* x    = (const float*)d_in[0];
  const float* wpe  = (const float*)d_in[1];
  const float* bpe  = (const float*)d_in[2];
  const float* pos  = (const float*)d_in[3];
  const float* ln1g = (const float*)d_in[4];
  const float* ln1b = (const float*)d_in[5];
  const float* wq   = (const float*)d_in[6];
  const float* bq   = (const float*)d_in[7];
  const float* wk   = (const float*)d_in[8];
  const float* bk   = (const float*)d_in[9];
  const float* wv   = (const float*)d_in[10];
  const float* bv   = (const float*)d_in[11];
  const float* wo   = (const float*)d_in[12];
  const float* bo   = (const float*)d_in[13];
  const float* ln2g = (const float*)d_in[14];
  const float* ln2b = (const float*)d_in[15];
  const float* w1   = (const float*)d_in[16];
  const float* bf1  = (const float*)d_in[17];
  const float* w2   = (const float*)d_in[18];
  const float* bf2  = (const float*)d_in[19];

  vit_fused<<<1024, 256, 0, stream>>>(x, wpe, bpe, pos, ln1g, ln1b, wq, bq, wk, bk,
                                      wv, bv, wo, bo, ln2g, ln2b, w1, bf1, w2, bf2,
                                      (float*)d_out);
}

// Round 13
// 80.550 us; speedup vs baseline: 1.1291x; 1.1291x over previous
//
#include <hip/hip_runtime.h>
#include <hip/hip_bf16.h>

typedef float          f32x4  __attribute__((ext_vector_type(4)));
typedef __bf16         bf16x8 __attribute__((ext_vector_type(8)));
typedef unsigned short u16x8  __attribute__((ext_vector_type(8)));
typedef unsigned int   u32;

#define DEV static __device__ __forceinline__

static constexpr int   NT       = 65536;            // (262144*4)/16 16-row tiles
static constexpr int   HALF     = NT / 2;
static constexpr float SCALE_Q2 = 0.2550349f;       // (1/sqrt(32)) * log2(e)  -> scores in log2 units

DEV unsigned short f2bf(float f) {
  return __builtin_bit_cast(unsigned short, __float2bfloat16(f));
}
// single-instruction RNE pair convert (gfx950)
DEV u32 pk2(float lo, float hi) {
  u32 r;
  asm("v_cvt_pk_bf16_f32 %0, %1, %2" : "=v"(r) : "v"(lo), "v"(hi));
  return r;
}

DEV u16x8 pack8(f32x4 a, f32x4 b) {
  uint4 q;
  q.x = pk2(a[0], a[1]); q.y = pk2(a[2], a[3]);
  q.z = pk2(b[0], b[1]); q.w = pk2(b[2], b[3]);
  return __builtin_bit_cast(u16x8, q);
}

DEV f32x4 mfma(u16x8 a, u16x8 b, f32x4 c) {
  return __builtin_amdgcn_mfma_f32_16x16x32_bf16(
      __builtin_bit_cast(bf16x8, a), __builtin_bit_cast(bf16x8, b), c, 0, 0, 0);
}
DEV void wait_lds() {
  asm volatile("s_waitcnt lgkmcnt(0)" ::: "memory");
  __builtin_amdgcn_sched_barrier(0);
}

// A-fragment of W^T for dout-column `col`, k-rows k0..k0+7.  W row-major [K][N], f32.
DEV u16x8 build_frag(const float* W, int N, int k0, int col, float scale) {
  u16x8 f;
#pragma unroll
  for (int e = 0; e < 8; ++e)
    f[e] = f2bf(W[(k0 + e) * N + col] * scale);
  return f;
}
DEV u16x8 fold_frag(u16x8 f, const float* gv) {
  u16x8 o;
#pragma unroll
  for (int e = 0; e < 8; ++e) {
    union { u32 i; float v; } u; u.i = ((u32)f[e]) << 16;
    o[e] = f2bf(u.v * gv[e]);
  }
  return o;
}

DEV void conv_wr(u32* buf, int wb, f32x4 a0, f32x4 a1) {
  buf[wb + 0] = pk2(a0[0], a0[1]);
  buf[wb + 1] = pk2(a0[2], a0[3]);
  buf[wb + 8] = pk2(a1[0], a1[1]);
  buf[wb + 9] = pk2(a1[2], a1[3]);
}
DEV u16x8 conv_rd(const u32* buf, int rb) {
  return __builtin_bit_cast(u16x8, *(const uint4*)(buf + rb));
}

DEV void ln_stats(f32x4 a, f32x4 b, float& rs, float& nm) {
  float s1 = 0.f, s2 = 0.f;
#pragma unroll
  for (int i = 0; i < 4; ++i) { s1 += a[i]; s2 = fmaf(a[i], a[i], s2); }
#pragma unroll
  for (int i = 0; i < 4; ++i) { s1 += b[i]; s2 = fmaf(b[i], b[i], s2); }
  s1 += __shfl_xor(s1, 16); s2 += __shfl_xor(s2, 16);
  s1 += __shfl_xor(s1, 32); s2 += __shfl_xor(s2, 32);
  const float m   = s1 * 0.03125f;
  const float var = fmaf(s2, 0.03125f, -m * m);
  rs = __builtin_amdgcn_rsqf(var + 1e-5f);
  nm = -m * rs;
}

// gelu(u) = u - u/(e+1),  e = exp2(u*(2.3022083 + 0.1029428 u^2))   (LOG2E pre-folded)
DEV float gelu_t(float u) {
  const float z = u * fmaf(u * u, 0.1029428f, 2.3022083f);
  const float e = __builtin_amdgcn_exp2f(z);
  return fmaf(-u, __builtin_amdgcn_rcpf(e + 1.0f), u);
}

__global__ __launch_bounds__(256) void vit_fused(
    const float* __restrict__ x,
    const float* __restrict__ wpe, const float* __restrict__ bpe,
    const float* __restrict__ pos,
    const float* __restrict__ ln1g, const float* __restrict__ ln1b,
    const float* __restrict__ wq, const float* __restrict__ bq,
    const float* __restrict__ wk, const float* __restrict__ bk,
    const float* __restrict__ wv, const float* __restrict__ bv,
    const float* __restrict__ wo, const float* __restrict__ bo,
    const float* __restrict__ ln2g, const float* __restrict__ ln2b,
    const float* __restrict__ w1, const float* __restrict__ bf1,
    const float* __restrict__ w2, const float* __restrict__ bf2,
    float* __restrict__ out) {
  const int tid = (int)threadIdx.x;
  const int wid = tid >> 6;
  const int l   = tid & 63;
  const int r15 = l & 15;        // row within 16-row tile (= 4 batches x 4 tokens)
  const int lg  = l >> 4;        // lane group 0..3
  const int tk  = l & 3;         // token index of this row

  __shared__ alignas(16) u32   s_conv[4][2][2][320]; // 20.0 KB  [wave][tile][buf]
  __shared__ alignas(16) float s_vh[4][2][576];      // 18.0 KB  [wave][tile] v/vo/h union
  u32*   cA[2] = { s_conv[wid][0][0], s_conv[wid][1][0] };
  u32*   cB[2] = { s_conv[wid][0][1], s_conv[wid][1][1] };
  float* vSf[2] = { s_vh[wid][0], s_vh[wid][1] };
  u32*   vSu[2] = { (u32*)s_vh[wid][0], (u32*)s_vh[wid][1] };

  // ---------------- init: persistent weight fragments + folded biases ----------------
  float g1v[8], g2v[8];
#pragma unroll
  for (int e = 0; e < 8; ++e) { g1v[e] = ln1g[8 * lg + e]; g2v[e] = ln2g[8 * lg + e]; }
  const u16x8 b1f = pack8(*(const f32x4*)(ln1b + 8 * lg), *(const f32x4*)(ln1b + 8 * lg + 4));
  const u16x8 b2f = pack8(*(const f32x4*)(ln2b + 8 * lg), *(const f32x4*)(ln2b + 8 * lg + 4));

  u16x8 wpeF[2], wqF[2], wkF[2], wvF[2], woF[2], w1F[4], w2F[2][2];
  f32x4 comboC[2], bqC[2], bkC[2], bvC[2], boC[2], bf2C[2], bf1C[4];

#pragma unroll
  for (int H = 0; H < 2; ++H) {
    const int dc  = 16 * H + 4 * lg;
    const int col = 16 * H + r15;
    wpeF[H]   = build_frag(wpe, 32, 8 * lg, col, 1.f);
    woF[H]    = build_frag(wo,  32, 8 * lg, col, 1.f);
    w2F[0][H] = build_frag(w2,  32, 8 * lg,      col, 1.f);
    w2F[1][H] = build_frag(w2,  32, 32 + 8 * lg, col, 1.f);
    f32x4 cq, ck, cv, cmb, cbo, cb2;
#pragma unroll
    for (int i = 0; i < 4; ++i) {
      const int d = dc + i;
      cmb[i] = bpe[d] + pos[tk * 32 + d];
      cq[i]  = SCALE_Q2 * bq[d];
      ck[i]  = bk[d];
      cv[i]  = bv[d];
      cbo[i] = bo[d];
      cb2[i] = bf2[d];
    }
    comboC[H] = cmb; boC[H] = cbo; bf2C[H] = cb2;
    const u16x8 rq = build_frag(wq, 32, 8 * lg, col, SCALE_Q2);
    const u16x8 rk = build_frag(wk, 32, 8 * lg, col, 1.f);
    const u16x8 rv = build_frag(wv, 32, 8 * lg, col, 1.f);
    bqC[H] = mfma(rq, b1f, cq);
    bkC[H] = mfma(rk, b1f, ck);
    bvC[H] = mfma(rv, b1f, cv);
    wqF[H] = fold_frag(rq, g1v);
    wkF[H] = fold_frag(rk, g1v);
    wvF[H] = fold_frag(rv, g1v);
  }
#pragma unroll
  for (int Hp = 0; Hp < 4; ++Hp) {
    const int col = 16 * Hp + r15;
    const u16x8 r1 = build_frag(w1, 64, 8 * lg, col, 1.f);
    f32x4 c1;
#pragma unroll
    for (int i = 0; i < 4; ++i) c1[i] = bf1[16 * Hp + 4 * lg + i];
    bf1C[Hp] = mfma(r1, b2f, c1);
    w1F[Hp]  = fold_frag(r1, g2v);
  }

  // ---------------- main loop: 2 tiles per wave (tile, tile+HALF) ----------------
  const f32x4 zero4 = {0.f, 0.f, 0.f, 0.f};
  const int stride = (int)(gridDim.x << 2);
  int tile = (int)(blockIdx.x << 2) | wid;

  const int xrow = r15 * 32 + 8 * lg;   // x load:  features 8lg..8lg+7
  const int orow = r15 * 32 + 4 * lg;   // C store: o0 -> 4lg..+3, o1 -> 16+4lg..+3
  f32x4 px0[2], px1[2];
  {
    const float* pa = x + (size_t)tile * 512 + xrow;
    const float* pb = x + (size_t)(tile + HALF) * 512 + xrow;
    px0[0] = *(const f32x4*)pa;       px1[0] = *(const f32x4*)(pa + 4);
    px0[1] = *(const f32x4*)pb;       px1[1] = *(const f32x4*)(pb + 4);
  }

  for (; tile < HALF; tile += stride) {
    const int nxt = tile + stride;
    f32x4 nx0[2] = {px0[0], px0[1]}, nx1[2] = {px1[0], px1[1]};
    if (nxt < HALF) {
      const float* pa = x + (size_t)nxt * 512 + xrow;
      const float* pb = x + (size_t)(nxt + HALF) * 512 + xrow;
      nx0[0] = *(const f32x4*)pa;     nx1[0] = *(const f32x4*)(pa + 4);
      nx0[1] = *(const f32x4*)pb;     nx1[1] = *(const f32x4*)(pb + 4);
    }
    const int wb = r15 * 20 + 2 * lg;
    const int rb = r15 * 20 + 4 * lg;

    // ---- S0: pe+pos -> x1 ; LN1 ; stage xa ----
    f32x4 x1a[2], x1b[2];
#pragma unroll
    for (int t = 0; t < 2; ++t) {
      const u16x8 xf = pack8(px0[t], px1[t]);
      x1a[t] = mfma(wpeF[0], xf, comboC[0]);
      x1b[t] = mfma(wpeF[1], xf, comboC[1]);
      float rs, nm;
      ln_stats(x1a[t], x1b[t], rs, nm);
      f32x4 ya, yb;
#pragma unroll
      for (int i = 0; i < 4; ++i) { ya[i] = fmaf(x1a[t][i], rs, nm); yb[i] = fmaf(x1b[t][i], rs, nm); }
      conv_wr(cA[t], wb, ya, yb);
    }
    wait_lds();

    // ---- S1: qkv projections ; stage q,k,v ----
#pragma unroll
    for (int t = 0; t < 2; ++t) {
      const u16x8 xaf = conv_rd(cA[t], rb);
      const f32x4 qa0 = mfma(wqF[0], xaf, bqC[0]);
      const f32x4 qa1 = mfma(wqF[1], xaf, bqC[1]);
      const f32x4 ka0 = mfma(wkF[0], xaf, bkC[0]);
      const f32x4 ka1 = mfma(wkF[1], xaf, bkC[1]);
      const f32x4 va0 = mfma(wvF[0], xaf, bvC[0]);
      const f32x4 va1 = mfma(wvF[1], xaf, bvC[1]);
      conv_wr(cB[t], wb, qa0, qa1);
      conv_wr(cA[t], wb, ka0, ka1);
      conv_wr(vSu[t], wb, va0, va1);
    }
    wait_lds();

    // ---- S2: vo = v@wo+bo ; scores ; softmax ; stage vo ; bpermute attn ----
    f32x4 atv[2];
#pragma unroll
    for (int t = 0; t < 2; ++t) {
      const u16x8 qf = conv_rd(cB[t], rb);
      const u16x8 kf = conv_rd(cA[t], rb);
      const u16x8 vf = conv_rd(vSu[t], rb);
      const f32x4 vo0 = mfma(woF[0], vf, boC[0]);
      const f32x4 vo1 = mfma(woF[1], vf, boC[1]);
      const f32x4 sc  = mfma(kf, qf, zero4);
      const float mx = fmaxf(fmaxf(sc[0], sc[1]), fmaxf(sc[2], sc[3]));
      const float e0 = __builtin_amdgcn_exp2f(sc[0] - mx);
      const float e1 = __builtin_amdgcn_exp2f(sc[1] - mx);
      const float e2 = __builtin_amdgcn_exp2f(sc[2] - mx);
      const float e3 = __builtin_amdgcn_exp2f(sc[3] - mx);
      const float rc = __builtin_amdgcn_rcpf((e0 + e1) + (e2 + e3));
      *(f32x4*)(vSf[t] + r15 * 36 + 4 * lg)      = vo0;
      *(f32x4*)(vSf[t] + r15 * 36 + 16 + 4 * lg) = vo1;
      const int srcb = (16 * (r15 >> 2) + r15) << 2;
      atv[t][0] = __builtin_bit_cast(float, __builtin_amdgcn_ds_bpermute(srcb, __builtin_bit_cast(int, e0 * rc)));
      atv[t][1] = __builtin_bit_cast(float, __builtin_amdgcn_ds_bpermute(srcb, __builtin_bit_cast(int, e1 * rc)));
      atv[t][2] = __builtin_bit_cast(float, __builtin_amdgcn_ds_bpermute(srcb, __builtin_bit_cast(int, e2 * rc)));
      atv[t][3] = __builtin_bit_cast(float, __builtin_amdgcn_ds_bpermute(srcb, __builtin_bit_cast(int, e3 * rc)));
    }
    wait_lds();

    // ---- S3: x2 = x1 + attn-mix(vo) ; LN2 ; stage xb ----
    f32x4 x2a[2], x2b[2];
#pragma unroll
    for (int t = 0; t < 2; ++t) {
      f32x4 m0 = zero4, m1 = zero4;
#pragma unroll
      for (int j = 0; j < 4; ++j) {
        const f32x4 v0 = *(const f32x4*)(vSf[t] + ((r15 & 12) + j) * 36 + 4 * lg);
        const f32x4 v1 = *(const f32x4*)(vSf[t] + ((r15 & 12) + j) * 36 + 16 + 4 * lg);
        m0 += atv[t][j] * v0;
        m1 += atv[t][j] * v1;
      }
      x2a[t] = x1a[t] + m0;
      x2b[t] = x1b[t] + m1;
      float rs, nm;
      ln_stats(x2a[t], x2b[t], rs, nm);
      f32x4 ya, yb;
#pragma unroll
      for (int i = 0; i < 4; ++i) { ya[i] = fmaf(x2a[t][i], rs, nm); yb[i] = fmaf(x2b[t][i], rs, nm); }
      conv_wr(cA[t], wb, ya, yb);
    }
    wait_lds();

    // ---- S4: MLP up + gelu ; stage h ----
#pragma unroll
    for (int t = 0; t < 2; ++t) {
      const u16x8 xbf = conv_rd(cA[t], rb);
      u32* hB = vSu[t];
#pragma unroll
      for (int Hp = 0; Hp < 4; ++Hp) {
        const f32x4 h = mfma(w1F[Hp], xbf, bf1C[Hp]);
        const int hb = r15 * 36 + 8 * Hp + 2 * lg;
        hB[hb]     = pk2(gelu_t(h[0]), gelu_t(h[1]));
        hB[hb + 1] = pk2(gelu_t(h[2]), gelu_t(h[3]));
      }
    }
    wait_lds();

    // ---- S5: MLP down + residual ; store ----
#pragma unroll
    for (int t = 0; t < 2; ++t) {
      const u32* hB = vSu[t];
      const u16x8 hf0 = __builtin_bit_cast(u16x8, *(const uint4*)(hB + r15 * 36 + 4 * lg));
      const u16x8 hf1 = __builtin_bit_cast(u16x8, *(const uint4*)(hB + r15 * 36 + 16 + 4 * lg));
      f32x4 o0 = x2a[t] + bf2C[0];
      f32x4 o1 = x2b[t] + bf2C[1];
      o0 = mfma(w2F[0][0], hf0, o0);
      o0 = mfma(w2F[1][0], hf1, o0);
      o1 = mfma(w2F[0][1], hf0, o1);
      o1 = mfma(w2F[1][1], hf1, o1);
      float* op = out + (size_t)(tile + t * HALF) * 512 + orow;
      *(f32x4*)(op)      = o0;
      *(f32x4*)(op + 16) = o1;
    }

    px0[0] = nx0[0]; px1[0] = nx1[0];
    px0[1] = nx0[1]; px1[1] = nx1[1];
  }
}

extern "C" void kernel_launch(void* const* d_in, const int* in_sizes, int n_in,
                              void* d_out, int out_size, void* d_ws, size_t ws_size,
                              hipStream_t stream) {
  (void)in_sizes; (void)n_in; (void)d_ws; (void)ws_size; (void)out_size;
  const float* x    = (const float*)d_in[0];
  const float* wpe  = (const float*)d_in[1];
  const float* bpe  = (const float*)d_in[2];
  const float* pos  = (const float*)d_in[3];
  const float* ln1g = (const float*)d_in[4];
  const float* ln1b = (const float*)d_in[5];
  const float* wq   = (const float*)d_in[6];
  const float* bq   = (const float*)d_in[7];
  const float* wk   = (const float*)d_in[8];
  const float* bk   = (const float*)d_in[9];
  const float* wv   = (const float*)d_in[10];
  const float* bv   = (const float*)d_in[11];
  const float* wo   = (const float*)d_in[12];
  const float* bo   = (const float*)d_in[13];
  const float* ln2g = (const float*)d_in[14];
  const float* ln2b = (const float*)d_in[15];
  const float* w1   = (const float*)d_in[16];
  const float* bf1  = (const float*)d_in[17];
  const float* w2   = (const float*)d_in[18];
  const float* bf2  = (const float*)d_in[19];

  vit_fused<<<1024, 256, 0, stream>>>(x, wpe, bpe, pos, ln1g, ln1b, wq, bq, wk, bk,
                                      wv, bv, wo, bo, ln2g, ln2b, w1, bf1, w2, bf2,
                                      (float*)d_out);
}

// Round 14
// 79.693 us; speedup vs baseline: 1.1412x; 1.0108x over previous
//
#include <hip/hip_runtime.h>
#include <hip/hip_bf16.h>

typedef float          f32x4  __attribute__((ext_vector_type(4)));
typedef __bf16         bf16x8 __attribute__((ext_vector_type(8)));
typedef unsigned short u16x8  __attribute__((ext_vector_type(8)));
typedef unsigned int   u32;

#define DEV static __device__ __forceinline__

static constexpr int   NT       = 65536;            // (262144*4)/16 16-row tiles
static constexpr int   HALF     = NT / 2;
static constexpr float SCALE_Q2 = 0.2550349f;       // (1/sqrt(32)) * log2(e)  -> scores in log2 units

DEV unsigned short f2bf(float f) {
  return __builtin_bit_cast(unsigned short, __float2bfloat16(f));
}
// single-instruction RNE pair convert (gfx950)
DEV u32 pk2(float lo, float hi) {
  u32 r;
  asm("v_cvt_pk_bf16_f32 %0, %1, %2" : "=v"(r) : "v"(lo), "v"(hi));
  return r;
}

DEV u16x8 pack8(f32x4 a, f32x4 b) {
  uint4 q;
  q.x = pk2(a[0], a[1]); q.y = pk2(a[2], a[3]);
  q.z = pk2(b[0], b[1]); q.w = pk2(b[2], b[3]);
  return __builtin_bit_cast(u16x8, q);
}

DEV f32x4 mfma(u16x8 a, u16x8 b, f32x4 c) {
  return __builtin_amdgcn_mfma_f32_16x16x32_bf16(
      __builtin_bit_cast(bf16x8, a), __builtin_bit_cast(bf16x8, b), c, 0, 0, 0);
}

// Zero-instruction compiler memory fence: orders this wave's LDS ops across the
// stage boundary.  Per-wave LDS execution is in-order on CDNA, and the backend
// inserts precise lgkmcnt(N) before each read's use — no full drain needed.
DEV void lds_fence() { asm volatile("" ::: "memory"); }

// A-fragment of W^T for dout-column `col`, k-rows k0..k0+7.  W row-major [K][N], f32.
DEV u16x8 build_frag(const float* W, int N, int k0, int col, float scale) {
  u16x8 f;
#pragma unroll
  for (int e = 0; e < 8; ++e)
    f[e] = f2bf(W[(k0 + e) * N + col] * scale);
  return f;
}
DEV u16x8 fold_frag(u16x8 f, const float* gv) {
  u16x8 o;
#pragma unroll
  for (int e = 0; e < 8; ++e) {
    union { u32 i; float v; } u; u.i = ((u32)f[e]) << 16;
    o[e] = f2bf(u.v * gv[e]);
  }
  return o;
}

DEV void conv_wr(u32* buf, int wb, f32x4 a0, f32x4 a1) {
  buf[wb + 0] = pk2(a0[0], a0[1]);
  buf[wb + 1] = pk2(a0[2], a0[3]);
  buf[wb + 8] = pk2(a1[0], a1[1]);
  buf[wb + 9] = pk2(a1[2], a1[3]);
}
DEV u16x8 conv_rd(const u32* buf, int rb) {
  return __builtin_bit_cast(u16x8, *(const uint4*)(buf + rb));
}

DEV void ln_stats(f32x4 a, f32x4 b, float& rs, float& nm) {
  float s1 = 0.f, s2 = 0.f;
#pragma unroll
  for (int i = 0; i < 4; ++i) { s1 += a[i]; s2 = fmaf(a[i], a[i], s2); }
#pragma unroll
  for (int i = 0; i < 4; ++i) { s1 += b[i]; s2 = fmaf(b[i], b[i], s2); }
  s1 += __shfl_xor(s1, 16); s2 += __shfl_xor(s2, 16);
  s1 += __shfl_xor(s1, 32); s2 += __shfl_xor(s2, 32);
  const float m   = s1 * 0.03125f;
  const float var = fmaf(s2, 0.03125f, -m * m);
  rs = __builtin_amdgcn_rsqf(var + 1e-5f);
  nm = -m * rs;
}

// gelu(u) = u - u/(e+1),  e = exp2(u*(2.3022083 + 0.1029428 u^2))   (LOG2E pre-folded)
DEV float gelu_t(float u) {
  const float z = u * fmaf(u * u, 0.1029428f, 2.3022083f);
  const float e = __builtin_amdgcn_exp2f(z);
  return fmaf(-u, __builtin_amdgcn_rcpf(e + 1.0f), u);
}

__global__ __launch_bounds__(256) void vit_fused(
    const float* __restrict__ x,
    const float* __restrict__ wpe, const float* __restrict__ bpe,
    const float* __restrict__ pos,
    const float* __restrict__ ln1g, const float* __restrict__ ln1b,
    const float* __restrict__ wq, const float* __restrict__ bq,
    const float* __restrict__ wk, const float* __restrict__ bk,
    const float* __restrict__ wv, const float* __restrict__ bv,
    const float* __restrict__ wo, const float* __restrict__ bo,
    const float* __restrict__ ln2g, const float* __restrict__ ln2b,
    const float* __restrict__ w1, const float* __restrict__ bf1,
    const float* __restrict__ w2, const float* __restrict__ bf2,
    float* __restrict__ out) {
  const int tid = (int)threadIdx.x;
  const int wid = tid >> 6;
  const int l   = tid & 63;
  const int r15 = l & 15;        // row within 16-row tile (= 4 batches x 4 tokens)
  const int lg  = l >> 4;        // lane group 0..3
  const int tk  = l & 3;         // token index of this row

  __shared__ alignas(16) u32   s_conv[4][2][2][320]; // 20.0 KB  [wave][tile][buf]
  __shared__ alignas(16) float s_vh[4][2][576];      // 18.0 KB  [wave][tile] v/vo/h union
  u32*   cA[2] = { s_conv[wid][0][0], s_conv[wid][1][0] };
  u32*   cB[2] = { s_conv[wid][0][1], s_conv[wid][1][1] };
  float* vSf[2] = { s_vh[wid][0], s_vh[wid][1] };
  u32*   vSu[2] = { (u32*)s_vh[wid][0], (u32*)s_vh[wid][1] };

  // ---------------- init: persistent weight fragments + folded biases ----------------
  float g1v[8], g2v[8];
#pragma unroll
  for (int e = 0; e < 8; ++e) { g1v[e] = ln1g[8 * lg + e]; g2v[e] = ln2g[8 * lg + e]; }
  const u16x8 b1f = pack8(*(const f32x4*)(ln1b + 8 * lg), *(const f32x4*)(ln1b + 8 * lg + 4));
  const u16x8 b2f = pack8(*(const f32x4*)(ln2b + 8 * lg), *(const f32x4*)(ln2b + 8 * lg + 4));

  u16x8 wpeF[2], wqF[2], wkF[2], wvF[2], woF[2], w1F[4], w2F[2][2];
  f32x4 comboC[2], bqC[2], bkC[2], bvC[2], boC[2], bf2C[2], bf1C[4];

#pragma unroll
  for (int H = 0; H < 2; ++H) {
    const int dc  = 16 * H + 4 * lg;
    const int col = 16 * H + r15;
    wpeF[H]   = build_frag(wpe, 32, 8 * lg, col, 1.f);
    woF[H]    = build_frag(wo,  32, 8 * lg, col, 1.f);
    w2F[0][H] = build_frag(w2,  32, 8 * lg,      col, 1.f);
    w2F[1][H] = build_frag(w2,  32, 32 + 8 * lg, col, 1.f);
    f32x4 cq, ck, cv, cmb, cbo, cb2;
#pragma unroll
    for (int i = 0; i < 4; ++i) {
      const int d = dc + i;
      cmb[i] = bpe[d] + pos[tk * 32 + d];
      cq[i]  = SCALE_Q2 * bq[d];
      ck[i]  = bk[d];
      cv[i]  = bv[d];
      cbo[i] = bo[d];
      cb2[i] = bf2[d];
    }
    comboC[H] = cmb; boC[H] = cbo; bf2C[H] = cb2;
    const u16x8 rq = build_frag(wq, 32, 8 * lg, col, SCALE_Q2);
    const u16x8 rk = build_frag(wk, 32, 8 * lg, col, 1.f);
    const u16x8 rv = build_frag(wv, 32, 8 * lg, col, 1.f);
    bqC[H] = mfma(rq, b1f, cq);
    bkC[H] = mfma(rk, b1f, ck);
    bvC[H] = mfma(rv, b1f, cv);
    wqF[H] = fold_frag(rq, g1v);
    wkF[H] = fold_frag(rk, g1v);
    wvF[H] = fold_frag(rv, g1v);
  }
#pragma unroll
  for (int Hp = 0; Hp < 4; ++Hp) {
    const int col = 16 * Hp + r15;
    const u16x8 r1 = build_frag(w1, 64, 8 * lg, col, 1.f);
    f32x4 c1;
#pragma unroll
    for (int i = 0; i < 4; ++i) c1[i] = bf1[16 * Hp + 4 * lg + i];
    bf1C[Hp] = mfma(r1, b2f, c1);
    w1F[Hp]  = fold_frag(r1, g2v);
  }

  // ---------------- main loop: 2 tiles per wave (tile, tile+HALF) ----------------
  const f32x4 zero4 = {0.f, 0.f, 0.f, 0.f};
  const int stride = (int)(gridDim.x << 2);
  int tile = (int)(blockIdx.x << 2) | wid;

  const int xrow = r15 * 32 + 8 * lg;   // x load:  features 8lg..8lg+7
  const int orow = r15 * 32 + 4 * lg;   // C store: o0 -> 4lg..+3, o1 -> 16+4lg..+3
  f32x4 px0[2], px1[2];
  {
    const float* pa = x + (size_t)tile * 512 + xrow;
    const float* pb = x + (size_t)(tile + HALF) * 512 + xrow;
    px0[0] = *(const f32x4*)pa;       px1[0] = *(const f32x4*)(pa + 4);
    px0[1] = *(const f32x4*)pb;       px1[1] = *(const f32x4*)(pb + 4);
  }

  for (; tile < HALF; tile += stride) {
    const int nxt = tile + stride;
    f32x4 nx0[2] = {px0[0], px0[1]}, nx1[2] = {px1[0], px1[1]};
    if (nxt < HALF) {
      const float* pa = x + (size_t)nxt * 512 + xrow;
      const float* pb = x + (size_t)(nxt + HALF) * 512 + xrow;
      nx0[0] = *(const f32x4*)pa;     nx1[0] = *(const f32x4*)(pa + 4);
      nx0[1] = *(const f32x4*)pb;     nx1[1] = *(const f32x4*)(pb + 4);
    }
    const int wb = r15 * 20 + 2 * lg;
    const int rb = r15 * 20 + 4 * lg;

    // ---- S0: pe+pos -> x1 ; LN1 ; stage xa ----
    f32x4 x1a[2], x1b[2];
#pragma unroll
    for (int t = 0; t < 2; ++t) {
      const u16x8 xf = pack8(px0[t], px1[t]);
      x1a[t] = mfma(wpeF[0], xf, comboC[0]);
      x1b[t] = mfma(wpeF[1], xf, comboC[1]);
      float rs, nm;
      ln_stats(x1a[t], x1b[t], rs, nm);
      f32x4 ya, yb;
#pragma unroll
      for (int i = 0; i < 4; ++i) { ya[i] = fmaf(x1a[t][i], rs, nm); yb[i] = fmaf(x1b[t][i], rs, nm); }
      conv_wr(cA[t], wb, ya, yb);
    }
    lds_fence();

    // ---- S1: qkv projections ; stage q,k,v ----
#pragma unroll
    for (int t = 0; t < 2; ++t) {
      const u16x8 xaf = conv_rd(cA[t], rb);
      const f32x4 qa0 = mfma(wqF[0], xaf, bqC[0]);
      const f32x4 qa1 = mfma(wqF[1], xaf, bqC[1]);
      const f32x4 ka0 = mfma(wkF[0], xaf, bkC[0]);
      const f32x4 ka1 = mfma(wkF[1], xaf, bkC[1]);
      const f32x4 va0 = mfma(wvF[0], xaf, bvC[0]);
      const f32x4 va1 = mfma(wvF[1], xaf, bvC[1]);
      conv_wr(cB[t], wb, qa0, qa1);
      conv_wr(cA[t], wb, ka0, ka1);
      conv_wr(vSu[t], wb, va0, va1);
    }
    lds_fence();

    // ---- S2: vo = v@wo+bo ; scores ; softmax ; stage vo ; bpermute attn ----
    f32x4 atv[2];
#pragma unroll
    for (int t = 0; t < 2; ++t) {
      const u16x8 qf = conv_rd(cB[t], rb);
      const u16x8 kf = conv_rd(cA[t], rb);
      const u16x8 vf = conv_rd(vSu[t], rb);
      const f32x4 vo0 = mfma(woF[0], vf, boC[0]);
      const f32x4 vo1 = mfma(woF[1], vf, boC[1]);
      const f32x4 sc  = mfma(kf, qf, zero4);
      const float mx = fmaxf(fmaxf(sc[0], sc[1]), fmaxf(sc[2], sc[3]));
      const float e0 = __builtin_amdgcn_exp2f(sc[0] - mx);
      const float e1 = __builtin_amdgcn_exp2f(sc[1] - mx);
      const float e2 = __builtin_amdgcn_exp2f(sc[2] - mx);
      const float e3 = __builtin_amdgcn_exp2f(sc[3] - mx);
      const float rc = __builtin_amdgcn_rcpf((e0 + e1) + (e2 + e3));
      *(f32x4*)(vSf[t] + r15 * 36 + 4 * lg)      = vo0;
      *(f32x4*)(vSf[t] + r15 * 36 + 16 + 4 * lg) = vo1;
      const int srcb = (16 * (r15 >> 2) + r15) << 2;
      atv[t][0] = __builtin_bit_cast(float, __builtin_amdgcn_ds_bpermute(srcb, __builtin_bit_cast(int, e0 * rc)));
      atv[t][1] = __builtin_bit_cast(float, __builtin_amdgcn_ds_bpermute(srcb, __builtin_bit_cast(int, e1 * rc)));
      atv[t][2] = __builtin_bit_cast(float, __builtin_amdgcn_ds_bpermute(srcb, __builtin_bit_cast(int, e2 * rc)));
      atv[t][3] = __builtin_bit_cast(float, __builtin_amdgcn_ds_bpermute(srcb, __builtin_bit_cast(int, e3 * rc)));
    }
    lds_fence();

    // ---- S3: x2 = x1 + attn-mix(vo) ; LN2 ; stage xb ----
    f32x4 x2a[2], x2b[2];
#pragma unroll
    for (int t = 0; t < 2; ++t) {
      f32x4 m0 = zero4, m1 = zero4;
#pragma unroll
      for (int j = 0; j < 4; ++j) {
        const f32x4 v0 = *(const f32x4*)(vSf[t] + ((r15 & 12) + j) * 36 + 4 * lg);
        const f32x4 v1 = *(const f32x4*)(vSf[t] + ((r15 & 12) + j) * 36 + 16 + 4 * lg);
        m0 += atv[t][j] * v0;
        m1 += atv[t][j] * v1;
      }
      x2a[t] = x1a[t] + m0;
      x2b[t] = x1b[t] + m1;
      float rs, nm;
      ln_stats(x2a[t], x2b[t], rs, nm);
      f32x4 ya, yb;
#pragma unroll
      for (int i = 0; i < 4; ++i) { ya[i] = fmaf(x2a[t][i], rs, nm); yb[i] = fmaf(x2b[t][i], rs, nm); }
      conv_wr(cA[t], wb, ya, yb);
    }
    lds_fence();

    // ---- S4: MLP up + gelu ; stage h ----
#pragma unroll
    for (int t = 0; t < 2; ++t) {
      const u16x8 xbf = conv_rd(cA[t], rb);
      u32* hB = vSu[t];
#pragma unroll
      for (int Hp = 0; Hp < 4; ++Hp) {
        const f32x4 h = mfma(w1F[Hp], xbf, bf1C[Hp]);
        const int hb = r15 * 36 + 8 * Hp + 2 * lg;
        hB[hb]     = pk2(gelu_t(h[0]), gelu_t(h[1]));
        hB[hb + 1] = pk2(gelu_t(h[2]), gelu_t(h[3]));
      }
    }
    lds_fence();

    // ---- S5: MLP down + residual ; store ----
#pragma unroll
    for (int t = 0; t < 2; ++t) {
      const u32* hB = vSu[t];
      const u16x8 hf0 = __builtin_bit_cast(u16x8, *(const uint4*)(hB + r15 * 36 + 4 * lg));
      const u16x8 hf1 = __builtin_bit_cast(u16x8, *(const uint4*)(hB + r15 * 36 + 16 + 4 * lg));
      f32x4 o0 = x2a[t] + bf2C[0];
      f32x4 o1 = x2b[t] + bf2C[1];
      o0 = mfma(w2F[0][0], hf0, o0);
      o0 = mfma(w2F[1][0], hf1, o0);
      o1 = mfma(w2F[0][1], hf0, o1);
      o1 = mfma(w2F[1][1], hf1, o1);
      float* op = out + (size_t)(tile + t * HALF) * 512 + orow;
      *(f32x4*)(op)      = o0;
      *(f32x4*)(op + 16) = o1;
    }

    px0[0] = nx0[0]; px1[0] = nx1[0];
    px0[1] = nx0[1]; px1[1] = nx1[1];
  }
}

extern "C" void kernel_launch(void* const* d_in, const int* in_sizes, int n_in,
                              void* d_out, int out_size, void* d_ws, size_t ws_size,
                              hipStream_t stream) {
  (void)in_sizes; (void)n_in; (void)d_ws; (void)ws_size; (void)out_size;
  const float* x    = (const float*)d_in[0];
  const float* wpe  = (const float*)d_in[1];
  const float* bpe  = (const float*)d_in[2];
  const float* pos  = (const float*)d_in[3];
  const float* ln1g = (const float*)d_in[4];
  const float* ln1b = (const float*)d_in[5];
  const float* wq   = (const float*)d_in[6];
  const float* bq   = (const float*)d_in[7];
  const float* wk   = (const float*)d_in[8];
  const float* bk   = (const float*)d_in[9];
  const float* wv   = (const float*)d_in[10];
  const float* bv   = (const float*)d_in[11];
  const float* wo   = (const float*)d_in[12];
  const float* bo   = (const float*)d_in[13];
  const float* ln2g = (const float*)d_in[14];
  const float* ln2b = (const float*)d_in[15];
  const float* w1   = (const float*)d_in[16];
  const float* bf1  = (const float*)d_in[17];
  const float* w2   = (const float*)d_in[18];
  const float* bf2  = (const float*)d_in[19];

  vit_fused<<<1024, 256, 0, stream>>>(x, wpe, bpe, pos, ln1g, ln1b, wq, bq, wk, bk,
                                      wv, bv, wo, bo, ln2g, ln2b, w1, bf1, w2, bf2,
                                      (float*)d_out);
}